// Round 1
// baseline (12.696 us; speedup 1.0000x reference)
//
#include <hip/hip_runtime.h>

#define B_DIM 32
#define S_DIM 16384
#define F_DIM 8
#define K_DIM 9
#define N_DIM (S_DIM - K_DIM)   // 16375

__global__ __launch_bounds__(256) void peak2peak_kernel(
    const float* __restrict__ x,
    const float* __restrict__ W,
    const float* __restrict__ bias,
    float* __restrict__ out)
{
    int tid = blockIdx.x * blockDim.x + threadIdx.x;
    const int total = B_DIM * N_DIM;
    if (tid >= total) return;

    int b = tid / N_DIM;
    int n = tid - b * N_DIM;

    const float* xrow = x + ((long)b * S_DIM + (long)n) * F_DIM;

    // Load W[:,0] (uniform scalar loads — W pointer is uniform, indices constant)
    float w0[F_DIM];
#pragma unroll
    for (int f = 0; f < F_DIM; ++f) w0[f] = W[f * K_DIM + 0];

    // base row
    float4 b0 = *reinterpret_cast<const float4*>(xrow);
    float4 b1 = *reinterpret_cast<const float4*>(xrow + 4);
    float base[F_DIM] = {
        b0.x * w0[0], b0.y * w0[1], b0.z * w0[2], b0.w * w0[3],
        b1.x * w0[4], b1.y * w0[5], b1.z * w0[6], b1.w * w0[7]
    };

    float acc[F_DIM] = {0.f, 0.f, 0.f, 0.f, 0.f, 0.f, 0.f, 0.f};

#pragma unroll
    for (int k = 0; k < K_DIM - 1; ++k) {
        float4 r0 = *reinterpret_cast<const float4*>(xrow + (long)k * F_DIM);
        float4 r1 = *reinterpret_cast<const float4*>(xrow + (long)k * F_DIM + 4);
        float rr[F_DIM] = { r0.x, r0.y, r0.z, r0.w, r1.x, r1.y, r1.z, r1.w };
#pragma unroll
        for (int f = 0; f < F_DIM; ++f) {
            acc[f] += fabsf(base[f] - rr[f] * W[f * K_DIM + (k + 1)]);
        }
    }

    float bb = bias[0];
    float4 o0 = { acc[0] + bb, acc[1] + bb, acc[2] + bb, acc[3] + bb };
    float4 o1 = { acc[4] + bb, acc[5] + bb, acc[6] + bb, acc[7] + bb };

    float* orow = out + (long)tid * F_DIM;
    *reinterpret_cast<float4*>(orow) = o0;
    *reinterpret_cast<float4*>(orow + 4) = o1;
}

extern "C" void kernel_launch(void* const* d_in, const int* in_sizes, int n_in,
                              void* d_out, int out_size, void* d_ws, size_t ws_size,
                              hipStream_t stream) {
    const float* x    = (const float*)d_in[0];
    const float* W    = (const float*)d_in[1];
    const float* bias = (const float*)d_in[2];
    float* out        = (float*)d_out;

    const int total  = B_DIM * N_DIM;           // 524000 rows
    const int block  = 256;
    const int grid   = (total + block - 1) / block;

    peak2peak_kernel<<<grid, block, 0, stream>>>(x, W, bias, out);
}

// Round 2
// 12.113 us; speedup vs baseline: 1.0481x; 1.0481x over previous
//
#include <hip/hip_runtime.h>

#define BATCH  32
#define S_DIM  16384
#define F_DIM  8
#define K_DIM  9
#define N_DIM  (S_DIM - K_DIM)   // 16375
#define NPB    256               // outputs per block
#define CHUNKS 528               // float4 chunks staged (264 rows x 2 halves)

// Block = 256 threads computes 256 consecutive output rows of one batch.
// Stage rows n0..n0+263 (8448 B) into LDS with coalesced float4 loads,
// XOR-swizzled so wave64 ds_read_b128 at lane-stride 32B is conflict-free:
//   chunk c = 2*row + half;  byte = (c ^ ((c>>3)&7)) << 4
// (c>>3 == row>>2 always, so read/write swizzles agree.)
__global__ __launch_bounds__(256) void peak2peak_kernel(
    const float* __restrict__ x,
    const float* __restrict__ W,
    const float* __restrict__ bias,
    float* __restrict__ out)
{
    __shared__ float4 lds4[CHUNKS];   // 8448 B

    const int t  = threadIdx.x;
    const int b  = blockIdx.y;
    const int n0 = blockIdx.x << 8;

    const float* xbase = x + ((long)b * S_DIM + n0) * F_DIM;
    const int climit = 2 * (S_DIM - n0);   // chunks whose row is in-bounds

#pragma unroll
    for (int i = 0; i < 3; ++i) {
        int c = t + i * 256;
        if (c < CHUNKS && c < climit) {
            float4 v = *reinterpret_cast<const float4*>(xbase + c * 4);
            *reinterpret_cast<float4*>(
                reinterpret_cast<char*>(lds4) + ((c ^ ((c >> 3) & 7)) << 4)) = v;
        }
    }
    __syncthreads();

    const float bb = bias[0];
    float res[F_DIM];

#pragma unroll
    for (int j = 0; j < 2; ++j) {       // feature half: f = 4j .. 4j+3
        float4 rv[8];
#pragma unroll
        for (int k = 0; k < 8; ++k) {
            int row = t + k;
            int byteoff = ((2 * row + j) ^ ((row >> 2) & 7)) << 4;
            rv[k] = *reinterpret_cast<const float4*>(
                reinterpret_cast<const char*>(lds4) + byteoff);
        }
        float rr0[4] = { rv[0].x, rv[0].y, rv[0].z, rv[0].w };
        float basev[4], acc[4];
#pragma unroll
        for (int f = 0; f < 4; ++f) {
            basev[f] = rr0[f] * W[(4 * j + f) * K_DIM];   // W[f,0], scalar loads
            acc[f]   = 0.f;
        }
#pragma unroll
        for (int k = 0; k < 8; ++k) {
            float rr[4] = { rv[k].x, rv[k].y, rv[k].z, rv[k].w };
#pragma unroll
            for (int f = 0; f < 4; ++f) {
                acc[f] += fabsf(basev[f] - rr[f] * W[(4 * j + f) * K_DIM + k + 1]);
            }
        }
#pragma unroll
        for (int f = 0; f < 4; ++f) res[4 * j + f] = acc[f] + bb;
    }

    const int n = n0 + t;
    if (n < N_DIM) {
        float* orow = out + ((long)b * N_DIM + n) * F_DIM;
        float4 o0 = { res[0], res[1], res[2], res[3] };
        float4 o1 = { res[4], res[5], res[6], res[7] };
        *reinterpret_cast<float4*>(orow)     = o0;
        *reinterpret_cast<float4*>(orow + 4) = o1;
    }
}

extern "C" void kernel_launch(void* const* d_in, const int* in_sizes, int n_in,
                              void* d_out, int out_size, void* d_ws, size_t ws_size,
                              hipStream_t stream) {
    const float* x    = (const float*)d_in[0];
    const float* W    = (const float*)d_in[1];
    const float* bias = (const float*)d_in[2];
    float* out        = (float*)d_out;

    dim3 grid(S_DIM / NPB, BATCH);   // 64 x 32 = 2048 blocks
    peak2peak_kernel<<<grid, 256, 0, stream>>>(x, W, bias, out);
}